// Round 1
// baseline (924.611 us; speedup 1.0000x reference)
//
#include <hip/hip_runtime.h>
#include <cstdint>
#include <cstddef>

namespace {

constexpr int N  = 50000;
constexpr int E  = 1600000;
constexpr int ET = E + N;          // edges + self loops
constexpr int F  = 256;
constexpr int H  = 6;
constexpr int C  = 16;
constexpr int HC = H * C;          // 96
constexpr int K  = 40;
constexpr int SCAN_B = (N + 255) / 256;  // 196

// ---------------- CSR construction ----------------

__global__ void hist_kernel(const int* __restrict__ ei, int* __restrict__ deg) {
  int e = blockIdx.x * blockDim.x + threadIdx.x;
  if (e >= ET) return;
  int dst = (e < E) ? ei[E + e] : (e - E);
  atomicAdd(&deg[dst], 1);
}

__global__ void scan1_kernel(const int* __restrict__ deg, int* __restrict__ rowp,
                             int* __restrict__ bs) {
  __shared__ int s[256];
  int t = threadIdx.x;
  int i = blockIdx.x * 256 + t;
  int v = (i < N) ? deg[i] : 0;
  s[t] = v;
  __syncthreads();
  for (int off = 1; off < 256; off <<= 1) {
    int tv = (t >= off) ? s[t - off] : 0;
    __syncthreads();
    s[t] += tv;
    __syncthreads();
  }
  if (i < N) rowp[i] = s[t] - v;  // local exclusive scan
  if (t == 255) bs[blockIdx.x] = s[255];
}

__global__ void scan2_kernel(int* __restrict__ bs, int* __restrict__ rowp) {
  if (threadIdx.x == 0 && blockIdx.x == 0) {
    int acc = 0;
    for (int b = 0; b < SCAN_B; b++) { int v = bs[b]; bs[b] = acc; acc += v; }
    rowp[N] = acc;  // == ET
  }
}

__global__ void scan3_kernel(int* __restrict__ rowp, const int* __restrict__ bs) {
  int i = blockIdx.x * 256 + threadIdx.x;
  if (i < N) rowp[i] += bs[blockIdx.x];
}

__global__ void fill_kernel(const int* __restrict__ ei, const int* __restrict__ rowp,
                            int* __restrict__ fillc, int* __restrict__ col) {
  int e = blockIdx.x * blockDim.x + threadIdx.x;
  if (e >= ET) return;
  int src, dst;
  if (e < E) { src = ei[e]; dst = ei[E + e]; }
  else       { src = e - E; dst = e - E; }
  int pos = atomicAdd(&fillc[dst], 1);
  col[rowp[dst] + pos] = src;
}

// ---------------- GEMM: out[nrows, NC] = A[nrows, KD] @ W[KD, NC] ----------------

template <int KD, int NC, int TN, int TM>
__global__ void gemm_kernel(const float* __restrict__ A, const float* __restrict__ W,
                            float* __restrict__ out, int nrows) {
  constexpr int TX = NC / TN;       // threads along cols
  constexpr int TY = 256 / TX;      // threads along rows
  constexpr int BM = TY * TM;       // rows per block
  constexpr int BK = 32;
  __shared__ float As[BM][BK + 1];
  __shared__ float Bs[BK][NC + 1];
  int tid = threadIdx.x;
  int tx = tid % TX, ty = tid / TX;
  int row0 = blockIdx.x * BM;
  float acc[TM][TN];
#pragma unroll
  for (int i = 0; i < TM; i++)
#pragma unroll
    for (int j = 0; j < TN; j++) acc[i][j] = 0.f;

  for (int k0 = 0; k0 < KD; k0 += BK) {
    for (int idx = tid; idx < BM * BK; idx += 256) {
      int r = idx / BK, c = idx % BK;
      int gr = row0 + r;
      As[r][c] = (gr < nrows) ? A[(size_t)gr * KD + k0 + c] : 0.f;
    }
    for (int idx = tid; idx < BK * NC; idx += 256) {
      int r = idx / NC, c = idx % NC;
      Bs[r][c] = W[(size_t)(k0 + r) * NC + c];
    }
    __syncthreads();
#pragma unroll
    for (int kk = 0; kk < BK; kk++) {
      float a[TM], b[TN];
#pragma unroll
      for (int i = 0; i < TM; i++) a[i] = As[ty * TM + i][kk];
#pragma unroll
      for (int j = 0; j < TN; j++) b[j] = Bs[kk][tx * TN + j];
#pragma unroll
      for (int i = 0; i < TM; i++)
#pragma unroll
        for (int j = 0; j < TN; j++) acc[i][j] += a[i] * b[j];
    }
    __syncthreads();
  }
#pragma unroll
  for (int i = 0; i < TM; i++) {
    int gr = row0 + ty * TM + i;
    if (gr >= nrows) continue;
#pragma unroll
    for (int j = 0; j < TN; j++)
      out[(size_t)gr * NC + tx * TN + j] = acc[i][j];
  }
}

// ---------------- attention logits: als/ald [N, HH] ----------------

template <int HH, int CC>
__global__ void logits_kernel(const float* __restrict__ h, const float* __restrict__ as_,
                              const float* __restrict__ ad_, float* __restrict__ als,
                              float* __restrict__ ald) {
  int t = blockIdx.x * blockDim.x + threadIdx.x;
  if (t >= N * HH) return;
  int n = t / HH, hh = t % HH;
  const float* hp = h + (size_t)n * (HH * CC) + (size_t)hh * CC;
  float ss = 0.f, dd = 0.f;
#pragma unroll
  for (int c = 0; c < CC; c++) {
    float v = hp[c];
    ss += v * as_[hh * CC + c];
    dd += v * ad_[hh * CC + c];
  }
  als[t] = ss;
  ald[t] = dd;
}

// ---------------- segment softmax stats (online max + sum) ----------------

template <int HH>
__global__ void stats_kernel(const int* __restrict__ rowp, const int* __restrict__ col,
                             const float* __restrict__ als, const float* __restrict__ ald,
                             float* __restrict__ mmax, float* __restrict__ dden) {
  int t = blockIdx.x * blockDim.x + threadIdx.x;
  if (t >= N * HH) return;
  int n = t / HH, hh = t % HH;
  float aldv = ald[t];
  int b0 = rowp[n], b1 = rowp[n + 1];
  float m = -1e30f, s = 0.f;
  for (int j = b0; j < b1; j++) {
    int src = col[j];
    float e = als[src * HH + hh] + aldv;
    e = (e > 0.f) ? e : 0.2f * e;
    if (e > m) { s *= __expf(m - e); m = e; }
    s += __expf(e - m);
  }
  mmax[t] = m;
  dden[t] = s;
}

// ---------------- aggregation (+bias, +relu or +log_softmax) ----------------

template <int HH, int CC, bool RELU, bool LSM>
__global__ void aggregate_kernel(const float* __restrict__ h, const int* __restrict__ rowp,
                                 const int* __restrict__ col, const float* __restrict__ als,
                                 const float* __restrict__ ald, const float* __restrict__ mmax,
                                 const float* __restrict__ dden, const float* __restrict__ bias,
                                 float* __restrict__ out) {
  int t = blockIdx.x * blockDim.x + threadIdx.x;
  if (t >= N * HH) return;
  int n = t / HH, hh = t % HH;
  float acc[CC];
#pragma unroll
  for (int c = 0; c < CC; c++) acc[c] = 0.f;
  float aldv = ald[t];
  float mv = mmax[t];
  float inv = 1.0f / (dden[t] + 1e-16f);
  int b0 = rowp[n], b1 = rowp[n + 1];
  for (int j = b0; j < b1; j++) {
    int s = col[j];
    float e = als[s * HH + hh] + aldv;
    e = (e > 0.f) ? e : 0.2f * e;
    float alpha = __expf(e - mv) * inv;
    const float* hs = h + (size_t)s * (HH * CC) + (size_t)hh * CC;
#pragma unroll
    for (int c = 0; c < CC; c++) acc[c] += alpha * hs[c];
  }
  if (LSM) {
    // single head, CC channels: add bias then row log_softmax
    float mx = -1e30f;
#pragma unroll
    for (int c = 0; c < CC; c++) {
      acc[c] += bias[c];
      mx = fmaxf(mx, acc[c]);
    }
    float ssum = 0.f;
#pragma unroll
    for (int c = 0; c < CC; c++) ssum += __expf(acc[c] - mx);
    float lse = mx + __logf(ssum);
#pragma unroll
    for (int c = 0; c < CC; c++) out[(size_t)n * CC + c] = acc[c] - lse;
  } else {
#pragma unroll
    for (int c = 0; c < CC; c++) {
      float v = acc[c] + bias[hh * CC + c];
      if (RELU) v = fmaxf(v, 0.f);
      out[(size_t)n * (HH * CC) + (size_t)hh * CC + c] = v;
    }
  }
}

inline int cdiv(int a, int b) { return (a + b - 1) / b; }

}  // namespace

extern "C" void kernel_launch(void* const* d_in, const int* in_sizes, int n_in,
                              void* d_out, int out_size, void* d_ws, size_t ws_size,
                              hipStream_t stream) {
  (void)in_sizes; (void)n_in; (void)out_size; (void)ws_size;
  const float* x   = (const float*)d_in[0];
  const int*   ei  = (const int*)d_in[1];
  const float* W1  = (const float*)d_in[2];
  const float* a1s = (const float*)d_in[3];
  const float* a1d = (const float*)d_in[4];
  const float* b1  = (const float*)d_in[5];
  const float* W2  = (const float*)d_in[6];
  const float* a2s = (const float*)d_in[7];
  const float* a2d = (const float*)d_in[8];
  const float* b2  = (const float*)d_in[9];
  const float* W3  = (const float*)d_in[10];
  const float* a3s = (const float*)d_in[11];
  const float* a3d = (const float*)d_in[12];
  const float* b3  = (const float*)d_in[13];
  const float* W4  = (const float*)d_in[14];
  const float* a4s = (const float*)d_in[15];
  const float* a4d = (const float*)d_in[16];
  const float* b4  = (const float*)d_in[17];
  float* out = (float*)d_out;

  char* ws = (char*)d_ws;
  size_t off = 0;
  auto alloc = [&](size_t bytes) {
    void* p = ws + off;
    off = (off + bytes + 255) & ~(size_t)255;
    return p;
  };
  int*   deg   = (int*)alloc((size_t)N * 4);
  int*   fillc = (int*)alloc((size_t)N * 4);
  int*   rowp  = (int*)alloc((size_t)(N + 1) * 4);
  int*   bs    = (int*)alloc((size_t)SCAN_B * 4);
  int*   col   = (int*)alloc((size_t)ET * 4);
  float* hbuf  = (float*)alloc((size_t)N * HC * 4);
  float* abuf  = (float*)alloc((size_t)N * HC * 4);
  float* als   = (float*)alloc((size_t)N * H * 4);
  float* ald   = (float*)alloc((size_t)N * H * 4);
  float* mm    = (float*)alloc((size_t)N * H * 4);
  float* dd    = (float*)alloc((size_t)N * H * 4);
  float* h4    = (float*)alloc((size_t)N * K * 4);

  // ---- build CSR ----
  hipMemsetAsync(deg, 0, (size_t)N * 4, stream);
  hipMemsetAsync(fillc, 0, (size_t)N * 4, stream);
  hist_kernel<<<cdiv(ET, 256), 256, 0, stream>>>(ei, deg);
  scan1_kernel<<<SCAN_B, 256, 0, stream>>>(deg, rowp, bs);
  scan2_kernel<<<1, 1, 0, stream>>>(bs, rowp);
  scan3_kernel<<<SCAN_B, 256, 0, stream>>>(rowp, bs);
  fill_kernel<<<cdiv(ET, 256), 256, 0, stream>>>(ei, rowp, fillc, col);

  const int gNH  = cdiv(N * H, 256);
  const int gN1  = cdiv(N, 256);
  const int gemmG = cdiv(N, 64);

  // ---- layer 1: x[N,256] -> act[N,96] ----
  gemm_kernel<F, HC, 6, 4><<<gemmG, 256, 0, stream>>>(x, W1, hbuf, N);
  logits_kernel<H, C><<<gNH, 256, 0, stream>>>(hbuf, a1s, a1d, als, ald);
  stats_kernel<H><<<gNH, 256, 0, stream>>>(rowp, col, als, ald, mm, dd);
  aggregate_kernel<H, C, true, false><<<gNH, 256, 0, stream>>>(hbuf, rowp, col, als, ald, mm, dd, b1, abuf);

  // ---- layer 2 ----
  gemm_kernel<HC, HC, 6, 4><<<gemmG, 256, 0, stream>>>(abuf, W2, hbuf, N);
  logits_kernel<H, C><<<gNH, 256, 0, stream>>>(hbuf, a2s, a2d, als, ald);
  stats_kernel<H><<<gNH, 256, 0, stream>>>(rowp, col, als, ald, mm, dd);
  aggregate_kernel<H, C, true, false><<<gNH, 256, 0, stream>>>(hbuf, rowp, col, als, ald, mm, dd, b2, abuf);

  // ---- layer 3 ----
  gemm_kernel<HC, HC, 6, 4><<<gemmG, 256, 0, stream>>>(abuf, W3, hbuf, N);
  logits_kernel<H, C><<<gNH, 256, 0, stream>>>(hbuf, a3s, a3d, als, ald);
  stats_kernel<H><<<gNH, 256, 0, stream>>>(rowp, col, als, ald, mm, dd);
  aggregate_kernel<H, C, true, false><<<gNH, 256, 0, stream>>>(hbuf, rowp, col, als, ald, mm, dd, b3, abuf);

  // ---- layer 4: act[N,96] -> h4[N,40], aggregate + log_softmax -> out ----
  gemm_kernel<HC, K, 5, 2><<<gemmG, 256, 0, stream>>>(abuf, W4, h4, N);
  logits_kernel<1, K><<<gN1, 256, 0, stream>>>(h4, a4s, a4d, als, ald);
  stats_kernel<1><<<gN1, 256, 0, stream>>>(rowp, col, als, ald, mm, dd);
  aggregate_kernel<1, K, false, true><<<gN1, 256, 0, stream>>>(h4, rowp, col, als, ald, mm, dd, b4, out);
}